// Round 3
// baseline (294.756 us; speedup 1.0000x reference)
//
#include <hip/hip_runtime.h>
#include <hip/hip_bf16.h>
#include <math.h>

typedef __bf16 bf16_t;
typedef __bf16 bf16x8 __attribute__((ext_vector_type(8)));
typedef float f32x4 __attribute__((ext_vector_type(4)));

enum { EP_BF16 = 0, EP_SCORES = 1, EP_F32 = 2 };

__device__ __forceinline__ void gload_lds16(const void* g, void* l) {
  __builtin_amdgcn_global_load_lds(
      (const __attribute__((address_space(1))) void*)g,
      (__attribute__((address_space(3))) void*)l, 16, 0, 0);
}

// XCD-aware swizzle; requires nwg % 8 == 0 (all our grids satisfy this)
__device__ __forceinline__ int xcd_swz(int bid, int nwg) {
  const int q = nwg >> 3;
  return (bid & 7) * q + (bid >> 3);
}

// ---------------------------------------------------------------------------
// Deep-pipelined GEMM core: C[row0+i][col0+j] = sum_k A[row0+i][k]*B[col0+j][k]
// A:[M][K], B:[N][K] row-major bf16. BK=32, BN=256, 8 waves (2Mx4N).
// TM = per-wave M-frags (8 -> BM=256, 4 -> BM=128).
// 4 LDS slots, stage depth 3 tiles ahead, counted vmcnt, T2 swizzle.
// ---------------------------------------------------------------------------

template <int TM, bool STG>
__device__ __forceinline__ void do_tile(char* smem, int slot, int sslot, size_t stoff,
                                        const char* const* gbase, const int* lbase,
                                        const int* aoff, const int* boff,
                                        f32x4 (&acc)[TM][4]) {
  bf16x8 bfr[4], af[4];
  if constexpr (TM == 8) {
    if constexpr (STG) {
      gload_lds16(gbase[0] + stoff, smem + sslot + lbase[0]);
      gload_lds16(gbase[1] + stoff, smem + sslot + lbase[1]);
    }
#pragma unroll
    for (int n = 0; n < 4; ++n) bfr[n] = *(const bf16x8*)(smem + slot + boff[n]);
#pragma unroll
    for (int m = 0; m < 4; ++m) af[m] = *(const bf16x8*)(smem + slot + aoff[m]);
    __builtin_amdgcn_s_setprio(1);
#pragma unroll
    for (int m = 0; m < 4; ++m)
#pragma unroll
      for (int n = 0; n < 4; ++n)
        acc[m][n] = __builtin_amdgcn_mfma_f32_16x16x32_bf16(af[m], bfr[n], acc[m][n], 0, 0, 0);
    __builtin_amdgcn_s_setprio(0);
    if constexpr (STG) __builtin_amdgcn_s_barrier();
    if constexpr (STG) {
      gload_lds16(gbase[2] + stoff, smem + sslot + lbase[2]);
      gload_lds16(gbase[3] + stoff, smem + sslot + lbase[3]);
    }
#pragma unroll
    for (int m = 0; m < 4; ++m) af[m] = *(const bf16x8*)(smem + slot + aoff[4 + m]);
    __builtin_amdgcn_s_setprio(1);
#pragma unroll
    for (int m = 0; m < 4; ++m)
#pragma unroll
      for (int n = 0; n < 4; ++n)
        acc[4 + m][n] = __builtin_amdgcn_mfma_f32_16x16x32_bf16(af[m], bfr[n], acc[4 + m][n], 0, 0, 0);
    __builtin_amdgcn_s_setprio(0);
  } else {
    if constexpr (STG) {
      gload_lds16(gbase[0] + stoff, smem + sslot + lbase[0]);
      gload_lds16(gbase[1] + stoff, smem + sslot + lbase[1]);
      gload_lds16(gbase[2] + stoff, smem + sslot + lbase[2]);
    }
#pragma unroll
    for (int n = 0; n < 4; ++n) bfr[n] = *(const bf16x8*)(smem + slot + boff[n]);
#pragma unroll
    for (int m = 0; m < 4; ++m) af[m] = *(const bf16x8*)(smem + slot + aoff[m]);
    __builtin_amdgcn_s_setprio(1);
#pragma unroll
    for (int m = 0; m < 4; ++m)
#pragma unroll
      for (int n = 0; n < 4; ++n)
        acc[m][n] = __builtin_amdgcn_mfma_f32_16x16x32_bf16(af[m], bfr[n], acc[m][n], 0, 0, 0);
    __builtin_amdgcn_s_setprio(0);
  }
}

template <int TM, int EPI>
__device__ __forceinline__ void gemm_core(
    const bf16_t* __restrict__ A, const bf16_t* __restrict__ B,
    void* __restrict__ Cout, int M, int N, int K,
    int row0, int col0, bool causal, float scale, char* smem)
{
  constexpr int BM = TM * 32;
  constexpr int LPT_A = BM / 128;        // staging rounds for A (8KB each)
  constexpr int LPT = LPT_A + 2;         // + 2 rounds for B (256 rows)
  constexpr int ABYTES = BM * 64;        // A bytes per slot
  constexpr int SLOT = (BM + 256) * 64;  // slot bytes

  const int tid = threadIdx.x;
  const int w = tid >> 6, lane = tid & 63;
  const int wr = w >> 2, wc = w & 3;

  int Keff = K;
  if (EPI == EP_F32 && causal) Keff = min(K, row0 + BM);
  const int nt = Keff >> 5;

  // --- staging addresses (pre-swizzled global source, linear LDS dest) ---
  const char* gbase[LPT];
  int lbase[LPT];
  {
    const int sd = (tid & 3) ^ ((tid >> 3) & 3);  // swizzled k-slot (involution)
    const int rrow = tid >> 2;                    // 0..127
#pragma unroll
    for (int r = 0; r < LPT; ++r) {
      const bool isA = (r < LPT_A);
      const int rr = isA ? r : (r - LPT_A);
      const int R = rr * 128 + rrow;
      const int grow = (isA ? row0 : col0) + R;
      const bf16_t* op = isA ? A : B;
      gbase[r] = (const char*)(op + (size_t)grow * K) + sd * 16;
      lbase[r] = (isA ? 0 : ABYTES) + rr * 8192 + w * 1024;  // wave-uniform
    }
  }

  // --- fragment read offsets (swizzled, matches source pre-swizzle) ---
  const int fl = lane & 15;
  const int arow_off = fl * 64 + (((lane >> 4) ^ ((fl >> 1) & 3)) * 16);
  int aoff[TM], boff[4];
#pragma unroll
  for (int m = 0; m < TM; ++m) aoff[m] = (wr * (TM * 16) + m * 16) * 64 + arow_off;
#pragma unroll
  for (int n = 0; n < 4; ++n) boff[n] = ABYTES + (wc * 64 + n * 16) * 64 + arow_off;

  f32x4 acc[TM][4] = {};

  // --- prologue: stage tiles 0..2 ---
  const int npro = nt < 3 ? nt : 3;
  for (int t = 0; t < npro; ++t)
#pragma unroll
    for (int r = 0; r < LPT; ++r)
      gload_lds16(gbase[r] + (size_t)t * 64, smem + (t & 3) * SLOT + lbase[r]);

  // --- main loop: compute tile t, stage tile t+3 ---
  const int nmain = nt - 3;
  for (int t = 0; t < nmain; ++t) {
    if constexpr (TM == 8) asm volatile("s_waitcnt vmcnt(8)" ::: "memory");
    else                   asm volatile("s_waitcnt vmcnt(6)" ::: "memory");
    __builtin_amdgcn_s_barrier();
    asm volatile("" ::: "memory");
    __builtin_amdgcn_sched_barrier(0);
    do_tile<TM, true>(smem, (t & 3) * SLOT, ((t + 3) & 3) * SLOT,
                      (size_t)(t + 3) * 64, gbase, lbase, aoff, boff, acc);
  }

  // --- drain ---
  asm volatile("s_waitcnt vmcnt(0)" ::: "memory");
  __builtin_amdgcn_s_barrier();
  asm volatile("" ::: "memory");
  __builtin_amdgcn_sched_barrier(0);
  for (int t = nmain > 0 ? nmain : 0; t < nt; ++t)
    do_tile<TM, false>(smem, (t & 3) * SLOT, 0, 0, gbase, lbase, aoff, boff, acc);

  // --- epilogue (C/D layout: col = lane&15, row = (lane>>4)*4 + i) ---
  const int cr = (lane >> 4) * 4;
  const int cc = lane & 15;
#pragma unroll
  for (int m = 0; m < TM; ++m) {
#pragma unroll
    for (int n = 0; n < 4; ++n) {
#pragma unroll
      for (int i = 0; i < 4; ++i) {
        const int r = row0 + wr * (TM * 16) + m * 16 + cr + i;
        const int c = col0 + wc * 64 + n * 16 + cc;
        float v = acc[m][n][i];
        if (EPI == EP_BF16) {
          ((bf16_t*)Cout)[(size_t)r * N + c] = (bf16_t)v;
        } else if (EPI == EP_SCORES) {
          v *= scale;
          if (causal && c > r) v = -INFINITY;
          ((float*)Cout)[(size_t)r * N + c] = v;
        } else {
          ((float*)Cout)[(size_t)r * N + c] = v;
        }
      }
    }
  }
}

// Launch A: q and k projections, exactly 256 blocks (128 q + 128 k)
__launch_bounds__(512, 2)
__global__ void qk_k(const bf16_t* __restrict__ qe16, const bf16_t* __restrict__ ie16,
                     const bf16_t* __restrict__ WqT, const bf16_t* __restrict__ WkT,
                     bf16_t* __restrict__ q16, bf16_t* __restrict__ k16) {
  extern __shared__ __align__(16) char smem[];
  int wg = xcd_swz(blockIdx.x, gridDim.x);
  const bf16_t *A, *B; bf16_t* C;
  if (wg < 128) { A = qe16; B = WqT; C = q16; }
  else          { A = ie16; B = WkT; C = k16; wg -= 128; }
  const int row0 = (wg >> 3) * 256, col0 = (wg & 7) * 256;  // M=4096, N=2048
  gemm_core<8, EP_BF16>(A, B, C, 4096, 2048, 2048, row0, col0, false, 1.f, smem);
}

// Launch B: v projection (128 blocks) + scores (packed causal: 136 active), grid 384
__launch_bounds__(512, 2)
__global__ void vs_k(const bf16_t* __restrict__ WvT, const bf16_t* __restrict__ ie16,
                     const bf16_t* __restrict__ q16, const bf16_t* __restrict__ k16,
                     bf16_t* __restrict__ vT16, float* __restrict__ scores,
                     const int* __restrict__ maskflag) {
  extern __shared__ __align__(16) char smem[];
  int wg = xcd_swz(blockIdx.x, gridDim.x);
  if (wg < 128) {
    // vT[d][s]: A = WvT [2048][2048], Bt = ie16 [4096][2048]
    const int row0 = (wg >> 4) * 256, col0 = (wg & 15) * 256;  // M=2048, N=4096
    gemm_core<8, EP_BF16>(WvT, ie16, vT16, 2048, 4096, 2048, row0, col0, false, 1.f, smem);
  } else {
    const int sid = wg - 128;
    const bool causal = maskflag[0] == 0;
    int r, c;
    if (causal) {
      if (sid >= 136) return;  // packed lower-triangle: 16*17/2 = 136 tiles
      r = (int)((sqrtf(8.f * (float)sid + 1.f) - 1.f) * 0.5f);
      while ((r + 1) * (r + 2) / 2 <= sid) ++r;
      while (r * (r + 1) / 2 > sid) --r;
      c = sid - r * (r + 1) / 2;
    } else {
      r = sid >> 4; c = sid & 15;
    }
    gemm_core<8, EP_SCORES>(q16, k16, scores, 4096, 4096, 2048,
                            r * 256, c * 256, causal, 0.1f, smem);
  }
}

// PV: out = probs @ v, TM=4 (BM=128), grid 256 exactly
template <int TM, int EPI>
__launch_bounds__(512, 2)
__global__ void gemm_k(const bf16_t* __restrict__ A, const bf16_t* __restrict__ B,
                       void* __restrict__ C, int M, int N, int K,
                       const int* __restrict__ maskflag, float scale) {
  extern __shared__ __align__(16) char smem[];
  const bool causal = (maskflag != nullptr) && (maskflag[0] == 0);
  constexpr int BM = TM * 32;
  const int ntn = N >> 8;
  const int wg = xcd_swz(blockIdx.x, gridDim.x);
  const int row0 = (wg / ntn) * BM, col0 = (wg % ntn) * 256;
  gemm_core<TM, EPI>(A, B, C, M, N, K, row0, col0, causal, scale, smem);
}

// ---------------------------------------------------------------------------

// z = 0: qe -> qe16 ; z = 1: ie -> ie16
__global__ void cvt_k(const float* __restrict__ qe, const float* __restrict__ ie,
                      bf16_t* __restrict__ qe16, bf16_t* __restrict__ ie16, long n) {
  const float* x = blockIdx.y ? ie : qe;
  bf16_t* y = blockIdx.y ? ie16 : qe16;
  long i = ((long)blockIdx.x * blockDim.x + threadIdx.x) * 8;
  const long stride = (long)gridDim.x * blockDim.x * 8;
  for (; i < n; i += stride) {
    const float4 a = *(const float4*)(x + i);
    const float4 b = *(const float4*)(x + i + 4);
    bf16x8 o;
    o[0] = (__bf16)a.x; o[1] = (__bf16)a.y; o[2] = (__bf16)a.z; o[3] = (__bf16)a.w;
    o[4] = (__bf16)b.x; o[5] = (__bf16)b.y; o[6] = (__bf16)b.z; o[7] = (__bf16)b.w;
    *(bf16x8*)(y + i) = o;
  }
}

// WT[n][k] = (bf16) W[k][n], z selects weight
__global__ void trans_k(const float* __restrict__ Wq, const float* __restrict__ Wk,
                        const float* __restrict__ Wv,
                        bf16_t* __restrict__ WqT, bf16_t* __restrict__ WkT,
                        bf16_t* __restrict__ WvT, int Dm) {
  const float* W = blockIdx.z == 0 ? Wq : (blockIdx.z == 1 ? Wk : Wv);
  bf16_t* WT = blockIdx.z == 0 ? WqT : (blockIdx.z == 1 ? WkT : WvT);
  __shared__ float tile[32][33];
  const int bx = blockIdx.x, by = blockIdx.y;
  const int tx = threadIdx.x & 31, ty = threadIdx.x >> 5;
#pragma unroll
  for (int r = ty; r < 32; r += 8)
    tile[r][tx] = W[(size_t)(by * 32 + r) * Dm + bx * 32 + tx];
  __syncthreads();
#pragma unroll
  for (int r = ty; r < 32; r += 8)
    WT[(size_t)(bx * 32 + r) * Dm + by * 32 + tx] = (bf16_t)tile[tx][r];
}

// one block per row; causal-aware: reads only j <= row
__global__ void softmax_rows(const float* __restrict__ Sc, bf16_t* __restrict__ P,
                             int n, const int* __restrict__ maskflag) {
  const int row = blockIdx.x;
  const int tid = threadIdx.x;
  const bool causal = maskflag[0] == 0;
  const int L = causal ? (row + 1) : n;
  const float* srow = Sc + (size_t)row * n;
  float v[16];
  float m = -INFINITY;
#pragma unroll
  for (int j = 0; j < 16; ++j) {
    const int idx = tid + j * 256;
    v[j] = (idx < L) ? srow[idx] : -INFINITY;
    m = fmaxf(m, v[j]);
  }
#pragma unroll
  for (int off = 32; off >= 1; off >>= 1) m = fmaxf(m, __shfl_xor(m, off));
  __shared__ float redm[4];
  __shared__ float reds[4];
  if ((tid & 63) == 0) redm[tid >> 6] = m;
  __syncthreads();
  m = fmaxf(fmaxf(redm[0], redm[1]), fmaxf(redm[2], redm[3]));
  float s = 0.f;
#pragma unroll
  for (int j = 0; j < 16; ++j) {
    v[j] = __expf(v[j] - m);
    s += v[j];
  }
#pragma unroll
  for (int off = 32; off >= 1; off >>= 1) s += __shfl_xor(s, off);
  if ((tid & 63) == 0) reds[tid >> 6] = s;
  __syncthreads();
  s = reds[0] + reds[1] + reds[2] + reds[3];
  const float inv = 1.f / s;
  bf16_t* prow = P + (size_t)row * n;
#pragma unroll
  for (int j = 0; j < 16; ++j) prow[tid + j * 256] = (bf16_t)(v[j] * inv);
}

extern "C" void kernel_launch(void* const* d_in, const int* in_sizes, int n_in,
                              void* d_out, int out_size, void* d_ws, size_t ws_size,
                              hipStream_t stream) {
  const float* ie = (const float*)d_in[0];
  const float* qe = (const float*)d_in[1];
  const float* Wq = (const float*)d_in[2];
  const float* Wk = (const float*)d_in[3];
  const float* Wv = (const float*)d_in[4];
  const int* mask = (const int*)d_in[5];
  float* out = (float*)d_out;

  const int S = 4096, D = 2048;
  char* ws = (char*)d_ws;
  const size_t MB = 1u << 20;
  // layout (peak 136 MB):
  //   0-16   q16        (dead after scores; overlaid by probs)
  //   16-32  k16        (dead after scores; overlaid by probs)
  //   32-48  vT16       (live to end)
  //   48-64  ie16       (dead after vs_k)
  //   64-72  WvT        (dead after vs_k)
  //   72-88  qe16       (dead after qk_k)
  //   88-96  WqT        (dead after qk_k)
  //   96-104 WkT        (dead after qk_k)
  //   72-136 scores     (written by vs_k, read by softmax)
  //   0-32   probs      (written by softmax, read by PV)
  bf16_t* q16  = (bf16_t*)(ws + 0 * MB);
  bf16_t* k16  = (bf16_t*)(ws + 16 * MB);
  bf16_t* vT16 = (bf16_t*)(ws + 32 * MB);
  bf16_t* ie16 = (bf16_t*)(ws + 48 * MB);
  bf16_t* WvT  = (bf16_t*)(ws + 64 * MB);
  bf16_t* qe16 = (bf16_t*)(ws + 72 * MB);
  bf16_t* WqT  = (bf16_t*)(ws + 88 * MB);
  bf16_t* WkT  = (bf16_t*)(ws + 96 * MB);
  float*  scores = (float*)(ws + 72 * MB);
  bf16_t* probs  = (bf16_t*)(ws + 0 * MB);

  hipFuncSetAttribute(reinterpret_cast<const void*>(&qk_k),
                      hipFuncAttributeMaxDynamicSharedMemorySize, 131072);
  hipFuncSetAttribute(reinterpret_cast<const void*>(&vs_k),
                      hipFuncAttributeMaxDynamicSharedMemorySize, 131072);
  hipFuncSetAttribute(reinterpret_cast<const void*>(&gemm_k<4, EP_F32>),
                      hipFuncAttributeMaxDynamicSharedMemorySize, 98304);

  // 1. casts + weight transposes
  cvt_k<<<dim3(1024, 2), 256, 0, stream>>>(qe, ie, qe16, ie16, (long)S * D);
  trans_k<<<dim3(D / 32, D / 32, 3), 256, 0, stream>>>(Wq, Wk, Wv, WqT, WkT, WvT, D);

  // 2. q,k projections: exactly 256 blocks
  qk_k<<<256, 512, 131072, stream>>>(qe16, ie16, WqT, WkT, q16, k16);

  // 3. v projection + scores (packed causal triangle), 264 active blocks
  vs_k<<<384, 512, 131072, stream>>>(WvT, ie16, q16, k16, vT16, scores, mask);

  // 4. causal-aware row softmax -> bf16 probs (overlays q16/k16)
  softmax_rows<<<S, 256, 0, stream>>>(scores, probs, S, mask);

  // 5. out = probs @ v, K truncated at causal boundary, 256 blocks
  gemm_k<4, EP_F32><<<256, 512, 98304, stream>>>(probs, vT16, out, S, D, S, mask, 1.f);
}

// Round 4
// 275.300 us; speedup vs baseline: 1.0707x; 1.0707x over previous
//
#include <hip/hip_runtime.h>
#include <hip/hip_bf16.h>
#include <math.h>

typedef __bf16 bf16_t;
typedef __bf16 bf16x8 __attribute__((ext_vector_type(8)));
typedef float f32x4 __attribute__((ext_vector_type(4)));

enum { EP_BF16 = 0, EP_SCORES = 1, EP_F32 = 2 };

#define MEMFENCE asm volatile("" ::: "memory")
#define BARRIER() do { MEMFENCE; __builtin_amdgcn_s_barrier(); MEMFENCE; } while (0)

__device__ __forceinline__ void gload_lds16(const void* g, void* l) {
  __builtin_amdgcn_global_load_lds(
      (const __attribute__((address_space(1))) void*)g,
      (__attribute__((address_space(3))) void*)l, 16, 0, 0);
}

// XCD-aware swizzle; requires nwg % 8 == 0
__device__ __forceinline__ int xcd_swz(int bid, int nwg) {
  const int q = nwg >> 3;
  return (bid & 7) * q + (bid >> 3);
}

// ---------------------------------------------------------------------------
// Deep-pipelined GEMM core: C[row0+i][col0+j] = sum_k A[row0+i][k]*B[col0+j][k]
// A:[M][K], B:[N][K] row-major bf16. BK=32, BN=256, 8 waves (2Mx4N).
// TM=8 -> BM=256, TM=4 -> BM=128. 4 LDS slots, depth-3 staging.
// m201-style phases: {reads; stage; BAR; lgkm(0); prio1 16xMFMA prio0; BAR},
// counted vmcnt once per K-tile (TM=8: 8, TM=4: 6), vmcnt(0) only at drain.
// ---------------------------------------------------------------------------

template <int TM, bool STG>
__device__ __forceinline__ void do_tile(char* smem, int slot, int sslot, size_t stoff,
                                        const char* const* gbase, const int* lbase,
                                        const int* aoff, const int* boff,
                                        f32x4 (&acc)[TM][4]) {
  bf16x8 bfr[4], af[4];
  if constexpr (TM == 8) {
    // ---- phase A: M-half 0 ----
#pragma unroll
    for (int n = 0; n < 4; ++n) bfr[n] = *(const bf16x8*)(smem + slot + boff[n]);
#pragma unroll
    for (int m = 0; m < 4; ++m) af[m] = *(const bf16x8*)(smem + slot + aoff[m]);
    if constexpr (STG) {
      gload_lds16(gbase[0] + stoff, smem + sslot + lbase[0]);
      gload_lds16(gbase[1] + stoff, smem + sslot + lbase[1]);
    }
    BARRIER();
    asm volatile("s_waitcnt lgkmcnt(0)" ::: "memory");
    __builtin_amdgcn_sched_barrier(0);
    __builtin_amdgcn_s_setprio(1);
#pragma unroll
    for (int m = 0; m < 4; ++m)
#pragma unroll
      for (int n = 0; n < 4; ++n)
        acc[m][n] = __builtin_amdgcn_mfma_f32_16x16x32_bf16(af[m], bfr[n], acc[m][n], 0, 0, 0);
    __builtin_amdgcn_s_setprio(0);
    BARRIER();
    // ---- phase B: M-half 1 ----
#pragma unroll
    for (int m = 0; m < 4; ++m) af[m] = *(const bf16x8*)(smem + slot + aoff[4 + m]);
    if constexpr (STG) {
      gload_lds16(gbase[2] + stoff, smem + sslot + lbase[2]);
      gload_lds16(gbase[3] + stoff, smem + sslot + lbase[3]);
      asm volatile("s_waitcnt vmcnt(8)" ::: "memory");  // retire oldest in-flight tile
    }
    BARRIER();
    asm volatile("s_waitcnt lgkmcnt(0)" ::: "memory");
    __builtin_amdgcn_sched_barrier(0);
    __builtin_amdgcn_s_setprio(1);
#pragma unroll
    for (int m = 0; m < 4; ++m)
#pragma unroll
      for (int n = 0; n < 4; ++n)
        acc[4 + m][n] = __builtin_amdgcn_mfma_f32_16x16x32_bf16(af[m], bfr[n], acc[4 + m][n], 0, 0, 0);
    __builtin_amdgcn_s_setprio(0);
    BARRIER();
  } else {
    // ---- single phase ----
#pragma unroll
    for (int n = 0; n < 4; ++n) bfr[n] = *(const bf16x8*)(smem + slot + boff[n]);
#pragma unroll
    for (int m = 0; m < 4; ++m) af[m] = *(const bf16x8*)(smem + slot + aoff[m]);
    if constexpr (STG) {
      gload_lds16(gbase[0] + stoff, smem + sslot + lbase[0]);
      gload_lds16(gbase[1] + stoff, smem + sslot + lbase[1]);
      gload_lds16(gbase[2] + stoff, smem + sslot + lbase[2]);
      asm volatile("s_waitcnt vmcnt(6)" ::: "memory");
    }
    BARRIER();
    asm volatile("s_waitcnt lgkmcnt(0)" ::: "memory");
    __builtin_amdgcn_sched_barrier(0);
    __builtin_amdgcn_s_setprio(1);
#pragma unroll
    for (int m = 0; m < 4; ++m)
#pragma unroll
      for (int n = 0; n < 4; ++n)
        acc[m][n] = __builtin_amdgcn_mfma_f32_16x16x32_bf16(af[m], bfr[n], acc[m][n], 0, 0, 0);
    __builtin_amdgcn_s_setprio(0);
    BARRIER();
  }
}

template <int TM, int EPI>
__device__ __forceinline__ void gemm_core(
    const bf16_t* __restrict__ A, const bf16_t* __restrict__ B,
    void* __restrict__ Cout, int M, int N, int K,
    int row0, int col0, bool causal, float scale, char* smem)
{
  constexpr int BM = TM * 32;
  constexpr int LPT_A = BM / 128;        // staging rounds for A (8KB each)
  constexpr int LPT = LPT_A + 2;         // + 2 rounds for B (256 rows)
  constexpr int ABYTES = BM * 64;        // A bytes per slot
  constexpr int SLOT = (BM + 256) * 64;  // slot bytes

  const int tid = threadIdx.x;
  const int w = tid >> 6, lane = tid & 63;
  const int wr = w >> 2, wc = w & 3;

  int Keff = K;
  if (EPI == EP_F32 && causal) Keff = min(K, row0 + BM);
  const int nt = Keff >> 5;

  // --- staging addresses (pre-swizzled global source, linear LDS dest) ---
  const char* gbase[LPT];
  int lbase[LPT];
  {
    const int sd = (tid & 3) ^ ((tid >> 3) & 3);  // swizzled k-slot (involution)
    const int rrow = tid >> 2;                    // 0..127
#pragma unroll
    for (int r = 0; r < LPT; ++r) {
      const bool isA = (r < LPT_A);
      const int rr = isA ? r : (r - LPT_A);
      const int grow = (isA ? row0 : col0) + rr * 128 + rrow;
      const bf16_t* op = isA ? A : B;
      gbase[r] = (const char*)(op + (size_t)grow * K) + sd * 16;
      lbase[r] = (isA ? 0 : ABYTES) + rr * 8192 + w * 1024;  // wave-uniform
    }
  }

  // --- fragment read offsets (swizzled, matches source pre-swizzle) ---
  const int fl = lane & 15;
  const int arow_off = fl * 64 + (((lane >> 4) ^ ((fl >> 1) & 3)) * 16);
  int aoff[TM], boff[4];
#pragma unroll
  for (int m = 0; m < TM; ++m) aoff[m] = (wr * (TM * 16) + m * 16) * 64 + arow_off;
#pragma unroll
  for (int n = 0; n < 4; ++n) boff[n] = ABYTES + (wc * 64 + n * 16) * 64 + arow_off;

  f32x4 acc[TM][4] = {};

  // --- prologue: stage tiles 0..2 ---
  const int npro = nt < 3 ? nt : 3;
  for (int t = 0; t < npro; ++t)
#pragma unroll
    for (int r = 0; r < LPT; ++r)
      gload_lds16(gbase[r] + (size_t)t * 64, smem + (t & 3) * SLOT + lbase[r]);

  // --- main loop: compute tile t, stage tile t+3 ---
  const int nmain = nt - 3;
  if (nmain > 0) {
    if constexpr (TM == 8) asm volatile("s_waitcnt vmcnt(8)" ::: "memory");
    else                   asm volatile("s_waitcnt vmcnt(6)" ::: "memory");
    BARRIER();
    for (int t = 0; t < nmain; ++t)
      do_tile<TM, true>(smem, (t & 3) * SLOT, ((t + 3) & 3) * SLOT,
                        (size_t)(t + 3) * 64, gbase, lbase, aoff, boff, acc);
  }

  // --- drain: everything already staged; counted waits invalid here -> drain 0 ---
  asm volatile("s_waitcnt vmcnt(0)" ::: "memory");
  BARRIER();
  for (int t = nmain > 0 ? nmain : 0; t < nt; ++t)
    do_tile<TM, false>(smem, (t & 3) * SLOT, 0, 0, gbase, lbase, aoff, boff, acc);

  // --- epilogue (C/D layout: col = lane&15, row = (lane>>4)*4 + i) ---
  const int cr = (lane >> 4) * 4;
  const int cc = lane & 15;
#pragma unroll
  for (int m = 0; m < TM; ++m) {
#pragma unroll
    for (int n = 0; n < 4; ++n) {
#pragma unroll
      for (int i = 0; i < 4; ++i) {
        const int r = row0 + wr * (TM * 16) + m * 16 + cr + i;
        const int c = col0 + wc * 64 + n * 16 + cc;
        float v = acc[m][n][i];
        if (EPI == EP_BF16) {
          ((bf16_t*)Cout)[(size_t)r * N + c] = (bf16_t)v;
        } else if (EPI == EP_SCORES) {
          v *= scale;
          if (causal && c > r) v = -INFINITY;
          ((float*)Cout)[(size_t)r * N + c] = v;
        } else {
          ((float*)Cout)[(size_t)r * N + c] = v;
        }
      }
    }
  }
}

// Launch A: q and k projections, exactly 256 blocks (128 q + 128 k)
__launch_bounds__(512, 2)
__global__ void qk_k(const bf16_t* __restrict__ qe16, const bf16_t* __restrict__ ie16,
                     const bf16_t* __restrict__ WqT, const bf16_t* __restrict__ WkT,
                     bf16_t* __restrict__ q16, bf16_t* __restrict__ k16) {
  extern __shared__ __align__(16) char smem[];
  int wg = xcd_swz(blockIdx.x, gridDim.x);
  const bf16_t *A, *B; bf16_t* C;
  if (wg < 128) { A = qe16; B = WqT; C = q16; }
  else          { A = ie16; B = WkT; C = k16; wg -= 128; }
  const int row0 = (wg >> 3) * 256, col0 = (wg & 7) * 256;  // M=4096, N=2048
  gemm_core<8, EP_BF16>(A, B, C, 4096, 2048, 2048, row0, col0, false, 1.f, smem);
}

// Launch B: scores (TM=8, long blocks, dispatched FIRST) + v projection (TM=4 short).
// causal:     ids [0,136) scores packed-triangle, [136,392) v, rest exit
// non-causal: ids [0,256) scores full,            [256,512) v
__launch_bounds__(512, 2)
__global__ void vs_k(const bf16_t* __restrict__ WvT, const bf16_t* __restrict__ ie16,
                     const bf16_t* __restrict__ q16, const bf16_t* __restrict__ k16,
                     bf16_t* __restrict__ vT16, float* __restrict__ scores,
                     const int* __restrict__ maskflag) {
  extern __shared__ __align__(16) char smem[];
  const bool causal = maskflag[0] == 0;
  const int bid = blockIdx.x;
  const int nsc = causal ? 136 : 256;
  if (bid < nsc) {
    const int sid = xcd_swz(bid, nsc);  // 136 = 8*17, 256: both % 8 == 0
    int r, c;
    if (causal) {
      r = (int)((sqrtf(8.f * (float)sid + 1.f) - 1.f) * 0.5f);
      while ((r + 1) * (r + 2) / 2 <= sid) ++r;
      while (r * (r + 1) / 2 > sid) --r;
      c = sid - r * (r + 1) / 2;
    } else {
      r = sid >> 4; c = sid & 15;
    }
    gemm_core<8, EP_SCORES>(q16, k16, scores, 4096, 4096, 2048,
                            r * 256, c * 256, causal, 0.1f, smem);
  } else {
    const int vloc = bid - nsc;
    if (vloc >= 256) return;
    const int wg = xcd_swz(vloc, 256);
    // vT[d][s]: A = WvT [2048][2048], Bt = ie16 [4096][2048], TM=4 (BM=128)
    const int row0 = (wg >> 4) * 128, col0 = (wg & 15) * 256;  // M=2048, N=4096
    gemm_core<4, EP_BF16>(WvT, ie16, vT16, 2048, 4096, 2048, row0, col0, false, 1.f, smem);
  }
}

// PV: out = probs @ v, TM=4 (BM=128), grid 256 exactly
template <int TM, int EPI>
__launch_bounds__(512, 2)
__global__ void gemm_k(const bf16_t* __restrict__ A, const bf16_t* __restrict__ B,
                       void* __restrict__ C, int M, int N, int K,
                       const int* __restrict__ maskflag, float scale) {
  extern __shared__ __align__(16) char smem[];
  const bool causal = (maskflag != nullptr) && (maskflag[0] == 0);
  constexpr int BM = TM * 32;
  const int ntn = N >> 8;
  const int wg = xcd_swz(blockIdx.x, gridDim.x);
  const int row0 = (wg / ntn) * BM, col0 = (wg % ntn) * 256;
  gemm_core<TM, EPI>(A, B, C, M, N, K, row0, col0, causal, scale, smem);
}

// ---------------------------------------------------------------------------

// y = 0: qe -> qe16 ; y = 1: ie -> ie16
__global__ void cvt_k(const float* __restrict__ qe, const float* __restrict__ ie,
                      bf16_t* __restrict__ qe16, bf16_t* __restrict__ ie16, long n) {
  const float* x = blockIdx.y ? ie : qe;
  bf16_t* y = blockIdx.y ? ie16 : qe16;
  long i = ((long)blockIdx.x * blockDim.x + threadIdx.x) * 8;
  const long stride = (long)gridDim.x * blockDim.x * 8;
  for (; i < n; i += stride) {
    const float4 a = *(const float4*)(x + i);
    const float4 b = *(const float4*)(x + i + 4);
    bf16x8 o;
    o[0] = (__bf16)a.x; o[1] = (__bf16)a.y; o[2] = (__bf16)a.z; o[3] = (__bf16)a.w;
    o[4] = (__bf16)b.x; o[5] = (__bf16)b.y; o[6] = (__bf16)b.z; o[7] = (__bf16)b.w;
    *(bf16x8*)(y + i) = o;
  }
}

// WT[n][k] = (bf16) W[k][n], z selects weight
__global__ void trans_k(const float* __restrict__ Wq, const float* __restrict__ Wk,
                        const float* __restrict__ Wv,
                        bf16_t* __restrict__ WqT, bf16_t* __restrict__ WkT,
                        bf16_t* __restrict__ WvT, int Dm) {
  const float* W = blockIdx.z == 0 ? Wq : (blockIdx.z == 1 ? Wk : Wv);
  bf16_t* WT = blockIdx.z == 0 ? WqT : (blockIdx.z == 1 ? WkT : WvT);
  __shared__ float tile[32][33];
  const int bx = blockIdx.x, by = blockIdx.y;
  const int tx = threadIdx.x & 31, ty = threadIdx.x >> 5;
#pragma unroll
  for (int r = ty; r < 32; r += 8)
    tile[r][tx] = W[(size_t)(by * 32 + r) * Dm + bx * 32 + tx];
  __syncthreads();
#pragma unroll
  for (int r = ty; r < 32; r += 8)
    WT[(size_t)(bx * 32 + r) * Dm + by * 32 + tx] = (bf16_t)tile[tx][r];
}

// one block per row; causal-aware: reads only j <= row
__global__ void softmax_rows(const float* __restrict__ Sc, bf16_t* __restrict__ P,
                             int n, const int* __restrict__ maskflag) {
  const int row = blockIdx.x;
  const int tid = threadIdx.x;
  const bool causal = maskflag[0] == 0;
  const int L = causal ? (row + 1) : n;
  const float* srow = Sc + (size_t)row * n;
  float v[16];
  float m = -INFINITY;
#pragma unroll
  for (int j = 0; j < 16; ++j) {
    const int idx = tid + j * 256;
    v[j] = (idx < L) ? srow[idx] : -INFINITY;
    m = fmaxf(m, v[j]);
  }
#pragma unroll
  for (int off = 32; off >= 1; off >>= 1) m = fmaxf(m, __shfl_xor(m, off));
  __shared__ float redm[4];
  __shared__ float reds[4];
  if ((tid & 63) == 0) redm[tid >> 6] = m;
  __syncthreads();
  m = fmaxf(fmaxf(redm[0], redm[1]), fmaxf(redm[2], redm[3]));
  float s = 0.f;
#pragma unroll
  for (int j = 0; j < 16; ++j) {
    v[j] = __expf(v[j] - m);
    s += v[j];
  }
#pragma unroll
  for (int off = 32; off >= 1; off >>= 1) s += __shfl_xor(s, off);
  if ((tid & 63) == 0) reds[tid >> 6] = s;
  __syncthreads();
  s = reds[0] + reds[1] + reds[2] + reds[3];
  const float inv = 1.f / s;
  bf16_t* prow = P + (size_t)row * n;
#pragma unroll
  for (int j = 0; j < 16; ++j) prow[tid + j * 256] = (bf16_t)(v[j] * inv);
}

extern "C" void kernel_launch(void* const* d_in, const int* in_sizes, int n_in,
                              void* d_out, int out_size, void* d_ws, size_t ws_size,
                              hipStream_t stream) {
  const float* ie = (const float*)d_in[0];
  const float* qe = (const float*)d_in[1];
  const float* Wq = (const float*)d_in[2];
  const float* Wk = (const float*)d_in[3];
  const float* Wv = (const float*)d_in[4];
  const int* mask = (const int*)d_in[5];
  float* out = (float*)d_out;

  const int S = 4096, D = 2048;
  char* ws = (char*)d_ws;
  const size_t MB = 1u << 20;
  bf16_t* q16  = (bf16_t*)(ws + 0 * MB);
  bf16_t* k16  = (bf16_t*)(ws + 16 * MB);
  bf16_t* vT16 = (bf16_t*)(ws + 32 * MB);
  bf16_t* ie16 = (bf16_t*)(ws + 48 * MB);
  bf16_t* WvT  = (bf16_t*)(ws + 64 * MB);
  bf16_t* qe16 = (bf16_t*)(ws + 72 * MB);
  bf16_t* WqT  = (bf16_t*)(ws + 88 * MB);
  bf16_t* WkT  = (bf16_t*)(ws + 96 * MB);
  float*  scores = (float*)(ws + 72 * MB);   // overlays qe16/WqT/WkT after qk_k
  bf16_t* probs  = (bf16_t*)(ws + 0 * MB);   // overlays q16/k16 after scores

  hipFuncSetAttribute(reinterpret_cast<const void*>(&qk_k),
                      hipFuncAttributeMaxDynamicSharedMemorySize, 131072);
  hipFuncSetAttribute(reinterpret_cast<const void*>(&vs_k),
                      hipFuncAttributeMaxDynamicSharedMemorySize, 131072);
  hipFuncSetAttribute(reinterpret_cast<const void*>(&gemm_k<4, EP_F32>),
                      hipFuncAttributeMaxDynamicSharedMemorySize, 98304);

  // 1. casts + weight transposes
  cvt_k<<<dim3(1024, 2), 256, 0, stream>>>(qe, ie, qe16, ie16, (long)S * D);
  trans_k<<<dim3(D / 32, D / 32, 3), 256, 0, stream>>>(Wq, Wk, Wv, WqT, WkT, WvT, D);

  // 2. q,k projections: exactly 256 blocks
  qk_k<<<256, 512, 131072, stream>>>(qe16, ie16, WqT, WkT, q16, k16);

  // 3. scores (long, first) + v projection (short, fills idle CUs), 512 blocks
  vs_k<<<512, 512, 131072, stream>>>(WvT, ie16, q16, k16, vT16, scores, mask);

  // 4. causal-aware row softmax -> bf16 probs
  softmax_rows<<<S, 256, 0, stream>>>(scores, probs, S, mask);

  // 5. out = probs @ v, K truncated at causal boundary, 256 blocks
  gemm_k<4, EP_F32><<<256, 512, 98304, stream>>>(probs, vT16, out, S, D, S, mask, 1.f);
}